// Round 10
// baseline (801.873 us; speedup 1.0000x reference)
//
#include <hip/hip_runtime.h>
#include <hip/hip_cooperative_groups.h>
#include <math.h>

namespace cg = cooperative_groups;

#define HH 240
#define WW 240
#define PP (HH * WW)
#define PW 242              // padded height/width for conv input
#define LOG_MAX_C 4.605170185988091f  // log(100)
#define LOG2E 1.442695040888963f

typedef __bf16 bf16x8 __attribute__((ext_vector_type(8)));
typedef float  f32x4  __attribute__((ext_vector_type(4)));

// native v_exp_f32 (2^x) — NOT __exp2f (glibc macro collision on gfx950 build)
#define EXP2F(x) __builtin_amdgcn_exp2f(x)

// ===========================================================================
// Layouts:
//  xs  [row][icb][px][32]      bf16  — conv B-fragment native (r7-verified)
//  wtf [tap][ocb][icb][512]    bf16  — conv A-fragment native
//  xpk [b*8+h][y][x][4]        fp32  — conv_in K output, PRE-NORMALIZED k-hat
//  xpv [b*8+h][y][x][4]        fp32  — conv_in V output (raw)
//  fq4 [b*8+h][y][x][4]        fp32  — conv_f Q output, PRE-SCALED
//  v1      [h][y][x][4]        fp32  — axial_row output, in d_out scratch
// History:
//  r10-r12: axial restructures -> ~43 us each. r11 KEPT: conv-epilogue
//       pre-norm K / pre-scale Q (win_attn/axials consume directly).
//  r13-r16: four conv experiments (XCD swizzle, B-in-LDS, fat blocks,
//       tri-buffer) all neutral-or-worse. Conv r3 body frozen.
//  r17: launch fusion 10 -> 6: 293 -> 265.6 us.
//  r18: transpose3 deleted (axial_col stages strided): 265.6 -> 257.1 us.
//  r19: COOPERATIVE MEGA-KERNEL: ~200 us of kernel time vs 257 wall ->
//       ~50 us is launch overhead + drain tails. One persistent grid,
//       5 stages, 4x grid.sync() (+threadfence for cross-XCD visibility).
//       Grid = occupancy-query x 256 CUs (co-residency guaranteed);
//       launch_bounds(256,4) caps VGPR at 128 (conv needs ~70, no spill);
//       15.4 KB shared pool reused across stages with leading-syncthreads
//       guards. All stage bodies verbatim -> absmax must stay 0.03912354.
// ===========================================================================

// ---------------- prep bodies ----------------------------------------------
__device__ __forceinline__ void to_xs_pad_body(
    int p, const float* __restrict__ in, __bf16* __restrict__ xs)
{
    if (p >= PW * PW) return;
    const int row = p / PW, px = p % PW;
    const bool border = (row == 0 || row == PW - 1 || px == 0 || px == PW - 1);
    union { __bf16 h[32]; uint4 u[4]; } pk;
#pragma unroll
    for (int icb = 0; icb < 3; ++icb) {
        uint4* op = (uint4*)(xs + (((size_t)row * 3 + icb) * PW + px) * 32);
        if (border) {
#pragma unroll
            for (int b = 0; b < 4; ++b) op[b] = make_uint4(0, 0, 0, 0);
        } else {
            const float* ip = in + (size_t)(icb * 32) * PP + (row - 1) * WW + (px - 1);
#pragma unroll
            for (int j = 0; j < 32; ++j) pk.h[j] = (__bf16)ip[(size_t)j * PP];
#pragma unroll
            for (int b = 0; b < 4; ++b) op[b] = pk.u[b];
        }
    }
}

__device__ __forceinline__ void wt_frag_body(
    int t, const float* __restrict__ w, __bf16* __restrict__ wtf, int OC)
{
    if (t >= 9 * (OC / 16) * 3 * 64) return;
    const int lane = t & 63;
    const int rest = t >> 6;
    const int icb  = rest % 3;
    const int to   = rest / 3;
    const int ocb  = to % (OC / 16);
    const int tap  = to / (OC / 16);
    const int ln = lane & 15, quad = lane >> 4;
    const int oc  = ocb * 16 + ln;
    const int ic0 = icb * 32 + quad * 8;
    __bf16* op = wtf + (size_t)rest * 512 + lane * 8;
#pragma unroll
    for (int d = 0; d < 8; ++d)
        op[d] = (__bf16)w[(size_t)(oc * 96 + ic0 + d) * 9 + tap];
}

// ---------------- conv body (exact r3 form, best measured) -----------------
// EPI: 0 = NCHW fp32 | 1 = xpk(k-hat)/xpv | 2 = fq4 (q-hat*scale*LOG2E)
template <int OC, int MT, int EPI>
__device__ __forceinline__ void conv_body(
    int bid, const __bf16* __restrict__ xs, const __bf16* __restrict__ wtf,
    const float* __restrict__ bias, float* __restrict__ out0,
    float* __restrict__ out1, const float* __restrict__ lsc,
    const float* __restrict__ lrlsc)
{
    const int group = bid / 24;
    const int w24   = bid % 24;
    const int z     = w24 >> 3;
    const int xy    = group * 8 + (w24 & 7);
    if (xy >= 450) return;
    const int x0  = (xy % 15) * 16;
    const int y0  = (xy / 15) * 8;
    const int oc0 = z * (MT * 16);
    const int ocb0 = oc0 / 16;

    const int wave = threadIdx.x >> 6;
    const int lane = threadIdx.x & 63;
    const int ln   = lane & 15;
    const int quad = lane >> 4;
    const int r0   = y0 + wave * 2;

    f32x4 acc[MT][2] = {};
    bf16x8 a[2][MT], b[2][2];

    const __bf16* abase = wtf + (size_t)lane * 8;
    const __bf16* bbase = xs + (size_t)ln * 32 + quad * 8;

#define LOAD_CHUNK(c, buf)                                                    \
    {                                                                         \
        const int tap_ = (c) / 3, icb_ = (c) % 3;                             \
        const int dy_ = tap_ / 3, dx_ = tap_ % 3;                             \
        const __bf16* ap_ = abase + (size_t)((tap_ * (OC / 16) + ocb0) * 3 + icb_) * 512; \
        _Pragma("unroll")                                                     \
        for (int mi = 0; mi < MT; ++mi)                                       \
            a[buf][mi] = *(const bf16x8*)(ap_ + (size_t)mi * 1536);           \
        _Pragma("unroll")                                                     \
        for (int ni = 0; ni < 2; ++ni)                                        \
            b[buf][ni] = *(const bf16x8*)(bbase +                             \
                (((size_t)(r0 + ni + dy_) * 3 + icb_) * PW + x0 + dx_) * 32); \
    }

    LOAD_CHUNK(0, 0)
#pragma unroll
    for (int c = 0; c < 27; ++c) {
        const int cur = c & 1, nxt = cur ^ 1;
        if (c < 26) LOAD_CHUNK(c + 1, nxt)
#pragma unroll
        for (int mi = 0; mi < MT; ++mi)
#pragma unroll
            for (int ni = 0; ni < 2; ++ni)
                acc[mi][ni] = __builtin_amdgcn_mfma_f32_16x16x32_bf16(
                    a[cur][mi], b[cur][ni], acc[mi][ni], 0, 0, 0);
    }
#undef LOAD_CHUNK

    if constexpr (EPI == 0) {
#pragma unroll
        for (int mi = 0; mi < MT; ++mi) {
#pragma unroll
            for (int r = 0; r < 4; ++r) {
                const int oc = oc0 + mi * 16 + quad * 4 + r;
                const float bv = bias[oc];
#pragma unroll
                for (int ni = 0; ni < 2; ++ni)
                    out0[(size_t)oc * PP + (r0 + ni) * WW + x0 + ln] = acc[mi][ni][r] + bv;
            }
        }
    } else if constexpr (EPI == 1) {
#pragma unroll
        for (int mi = 0; mi < MT; ++mi) {
            const f32x4 bv = *(const f32x4*)(bias + oc0 + mi * 16 + quad * 4);
            float* dst = (mi >> 1) ? out1 : out0;
            const int h8 = z * 8 + (mi & 1) * 4 + quad;
#pragma unroll
            for (int ni = 0; ni < 2; ++ni) {
                f32x4 o = acc[mi][ni] + bv;
                if ((mi >> 1) == 0) {  // K side: store k-hat
                    const float ksq = o[0]*o[0] + o[1]*o[1] + o[2]*o[2] + o[3]*o[3];
                    o *= 1.0f / fmaxf(sqrtf(ksq), 1e-12f);
                }
                *(f32x4*)(dst + (((size_t)h8 * 240 + r0 + ni) * 240 + x0 + ln) * 4) = o;
            }
        }
    } else {
#pragma unroll
        for (int mi = 0; mi < MT; ++mi) {
            const f32x4 bv = *(const f32x4*)(bias + oc0 + mi * 16 + quad * 4);
            const int h8 = z * 8 + mi * 4 + quad;
            const int br = h8 >> 3, hh = h8 & 7;
            const float ls = (br == 2) ? lrlsc[hh] : lsc[hh];
            const float qsc = __expf(fminf(ls, LOG_MAX_C)) * LOG2E;
#pragma unroll
            for (int ni = 0; ni < 2; ++ni) {
                f32x4 o = acc[mi][ni] + bv;
                const float qsq = o[0]*o[0] + o[1]*o[1] + o[2]*o[2] + o[3]*o[3];
                o *= qsc / fmaxf(sqrtf(qsq), 1e-12f);
                *(f32x4*)(out0 + (((size_t)h8 * 240 + r0 + ni) * 240 + x0 + ln) * 4) = o;
            }
        }
    }
}

// ---------------- attn stage body (axial_row | win_attn | zero_border) -----
__device__ __forceinline__ void attn_body(
    int item, const float* __restrict__ fq4, const float* __restrict__ xpk,
    const float* __restrict__ xpv, const float* __restrict__ lsc,
    const float* __restrict__ lrlsc, __bf16* __restrict__ ys,
    float* __restrict__ v1, f32x4* sm)
{
    const int t = threadIdx.x;
    __syncthreads();   // LDS-reuse guard across persistent-loop iterations

    if (item < 960) {
        // ---- axial_row: 2 rows/block, 2 queries/thread (r12 structure)
        const int bx = item >> 3, h = item & 7;
        const int half = t >> 7, tl = t & 127;
        const int y = bx * 2 + half;
        f32x4* ks = sm;            // [2][240]
        f32x4* vs = sm + 480;      // [2][240]

        const float scale = __expf(fminf(lrlsc[h], LOG_MAX_C));
        const float negM2 = -scale * LOG2E;
        const size_t rowb = ((size_t)h * 240 + y) * 240;
        const float* fq4b = fq4 + 64 * PP;
        const float* xpkb = xpk + 64 * PP;
        const float* xpvb = xpv + 64 * PP;
        f32x4 qreg[2] = {};

        if (tl < 120) {
#pragma unroll
            for (int s = 0; s < 2; ++s) {
                const int i = tl + s * 120;
                const size_t p4 = (rowb + i) * 4;
                ks[half * 240 + i] = *(const f32x4*)(xpkb + p4);
                vs[half * 240 + i] = *(const f32x4*)(xpvb + p4);
                qreg[s] = *(const f32x4*)(fq4b + p4);
            }
        }
        __syncthreads();
        if (tl < 120) {
            float l0 = 0.f, l1 = 0.f;
            f32x4 a0 = {0, 0, 0, 0}, a1 = {0, 0, 0, 0};
#pragma unroll 4
            for (int j = 0; j < 240; ++j) {
                const f32x4 kk = ks[half * 240 + j];
                const f32x4 vv = vs[half * 240 + j];
                const float s0 = fmaf(qreg[0][0], kk[0],
                                 fmaf(qreg[0][1], kk[1],
                                 fmaf(qreg[0][2], kk[2],
                                 fmaf(qreg[0][3], kk[3], negM2))));
                const float s1 = fmaf(qreg[1][0], kk[0],
                                 fmaf(qreg[1][1], kk[1],
                                 fmaf(qreg[1][2], kk[2],
                                 fmaf(qreg[1][3], kk[3], negM2))));
                const float p0 = EXP2F(s0);
                const float p1 = EXP2F(s1);
                l0 += p0; l1 += p1;
                a0 += vv * p0;
                a1 += vv * p1;
            }
            *(f32x4*)(v1 + (rowb + tl) * 4) = a0 * (1.0f / l0);
            *(f32x4*)(v1 + (rowb + tl + 120) * 4) = a1 * (1.0f / l1);
        }
    } else if (item < 5568) {
        // ---- win_attn branches 0+1 (r11 pre-scaled inputs)
        const int id2 = item - 960;
        const int br  = id2 / 2304;          // 0: plain, 1: shifted
        const int id  = id2 % 2304;
        const int wi  = id / 288;
        const int g   = id % 288;
        const int wy  = g / 6;
        const int wx  = (g % 6) * 8 + wi;
        const int gshift = br * 3, sshift = br * 2;
        const size_t choff = (size_t)br * 32 * PP;
        const int h = t / 25, i = t % 25;
        f32x4* ks = sm;            // [8][25]
        f32x4* vs = sm + 200;      // [8][25]
        f32x4 qn = {0, 0, 0, 0};
        float negM2 = 0.f;
        int oy = 0, ox = 0;

        if (t < 200) {
            const int y = (wy * 5 + i / 5 + gshift) % HH;
            const int x = (wx * 5 + i % 5 + gshift) % WW;
            const size_t p4 = choff + (((size_t)h * 240 + y) * 240 + x) * 4;
            qn = *(const f32x4*)(fq4 + p4);              // pre-scaled q
            ks[h * 25 + i] = *(const f32x4*)(xpk + p4);  // pre-normalized k
            vs[h * 25 + i] = *(const f32x4*)(xpv + p4);
            const float scale = __expf(fminf(lsc[h], LOG_MAX_C));
            negM2 = -scale * LOG2E;
            oy = (wy * 5 + i / 5 + sshift) % HH;
            ox = (wx * 5 + i % 5 + sshift) % WW;
        }
        __syncthreads();
        if (t < 200) {
            float l = 0.f;
            f32x4 acc = {0, 0, 0, 0};
#pragma unroll
            for (int j = 0; j < 25; ++j) {
                const f32x4 kk = ks[h * 25 + j];
                const float s = fmaf(qn[0], kk[0],
                                fmaf(qn[1], kk[1],
                                fmaf(qn[2], kk[2],
                                fmaf(qn[3], kk[3], negM2))));
                const float p = EXP2F(s);
                l += p;
                acc += vs[h * 25 + j] * p;
            }
            const float linv = 1.0f / l;
            union { __bf16 h4[4]; uint2 u; } o;
#pragma unroll
            for (int d = 0; d < 4; ++d) o.h4[d] = (__bf16)(acc[d] * linv);
            *(uint2*)(ys + (((size_t)(oy + 1) * 3 + br) * PW + ox + 1) * 32 + h * 4) = o.u;
        }
    } else {
        // ---- zero_border of ys
        const int idx = (item - 5568) * 256 + t;
        if (idx >= 4 * PW) return;
        const int g = idx / PW, i = idx % PW;
        int row, px;
        if (g == 0)      { row = 0;      px = i; }
        else if (g == 1) { row = PW - 1; px = i; }
        else if (g == 2) { row = i;      px = 0; }
        else             { row = i;      px = PW - 1; }
#pragma unroll
        for (int icb = 0; icb < 3; ++icb) {
            uint4* op = (uint4*)(ys + (((size_t)row * 3 + icb) * PW + px) * 32);
#pragma unroll
            for (int b = 0; b < 4; ++b) op[b] = make_uint4(0, 0, 0, 0);
        }
    }
}

// ---------------- axial_col body (r18 strided staging) ---------------------
__device__ __forceinline__ void axial_col_body(
    int item, const float* __restrict__ knb, const float* __restrict__ qnb,
    const float* __restrict__ v1b, const float* __restrict__ lsc,
    __bf16* __restrict__ ys, f32x4* sm)
{
    const int t = threadIdx.x;
    __syncthreads();   // LDS-reuse guard

    f32x4* ks = sm;            // [2][240]
    f32x4* vs = sm + 480;      // [2][240]
    const int wi  = item / 120;           // 0..7
    const int g   = item % 120;
    const int h   = g % 8;
    const int xc  = g / 8;                // 0..14
    const int half = t >> 7, tl = t & 127;
    const int x = xc * 16 + wi * 2 + half;

    const float scale = __expf(fminf(lsc[h], LOG_MAX_C));
    const float negM2 = -scale * LOG2E;
    const size_t hb = (size_t)h * 240;
    f32x4 qreg[2] = {};

    if (tl < 120) {
#pragma unroll
        for (int s = 0; s < 2; ++s) {
            const int i = tl + s * 120;          // y position
            const size_t p4 = ((hb + i) * 240 + x) * 4;
            ks[half * 240 + i] = *(const f32x4*)(knb + p4);
            vs[half * 240 + i] = *(const f32x4*)(v1b + p4);
            qreg[s] = *(const f32x4*)(qnb + p4);
        }
    }
    __syncthreads();
    if (tl < 120) {
        float l0 = 0.f, l1 = 0.f;
        f32x4 a0 = {0, 0, 0, 0}, a1 = {0, 0, 0, 0};
#pragma unroll 4
        for (int j = 0; j < 240; ++j) {
            const f32x4 kk = ks[half * 240 + j];
            const f32x4 vv = vs[half * 240 + j];
            const float s0 = fmaf(qreg[0][0], kk[0],
                             fmaf(qreg[0][1], kk[1],
                             fmaf(qreg[0][2], kk[2],
                             fmaf(qreg[0][3], kk[3], negM2))));
            const float s1 = fmaf(qreg[1][0], kk[0],
                             fmaf(qreg[1][1], kk[1],
                             fmaf(qreg[1][2], kk[2],
                             fmaf(qreg[1][3], kk[3], negM2))));
            const float p0 = EXP2F(s0);
            const float p1 = EXP2F(s1);
            l0 += p0; l1 += p1;
            a0 += vv * p0;
            a1 += vv * p1;
        }
#pragma unroll
        for (int s = 0; s < 2; ++s) {
            const f32x4 o4 = s ? a1 * (1.0f / l1) : a0 * (1.0f / l0);
            const int i = tl + s * 120;
            union { __bf16 h4[4]; uint2 u; } o;
#pragma unroll
            for (int d = 0; d < 4; ++d) o.h4[d] = (__bf16)o4[d];
            *(uint2*)(ys + (((size_t)(i + 1) * 3 + 2) * PW + x + 1) * 32 + h * 4) = o.u;
        }
    }
}

// ---------------------------------------------------------------------------
// Cooperative mega-kernel: 5 stages, 4 grid syncs, persistent grid.
// ---------------------------------------------------------------------------
__global__ __launch_bounds__(256, 4) void mega(
    const float* __restrict__ x, const float* __restrict__ w_in,
    const float* __restrict__ b_in, const float* __restrict__ w_f,
    const float* __restrict__ b_f, const float* __restrict__ w_out,
    const float* __restrict__ b_out, const float* __restrict__ lsc,
    const float* __restrict__ lrlsc, float* __restrict__ out,
    float* __restrict__ ws)
{
    __shared__ f32x4 sm[960];          // 15.36 KB pool, reused by stages 2/3
    float* xpk = ws;                   // 96*PP
    float* xpv = xpk + 96 * PP;        // 96*PP
    float* fq4 = xpv + 96 * PP;        // 96*PP
    __bf16* xs     = (__bf16*)(fq4 + 96 * PP);
    __bf16* wtf_in = xs + (size_t)PW * 3 * PW * 32;
    __bf16* wtf_f  = wtf_in + 9 * 12 * 3 * 512;
    __bf16* wtf_o  = wtf_f + 9 * 6 * 3 * 512;
    __bf16* ys     = xs;               // alias: xs dead after stage 1 (conv)
    float* v1      = out;              // d_out scratch, dead until stage 4

    const int nb = gridDim.x;
    cg::grid_group grid = cg::this_grid();

    // ---- stage 0: prep (3x wt_frag + to_xs_pad), 392 items
    for (int i = blockIdx.x; i < 392; i += nb) {
        const int tid = threadIdx.x;
        if (i < 81)       wt_frag_body(i * 256 + tid, w_in, wtf_in, 192);
        else if (i < 122) wt_frag_body((i - 81) * 256 + tid, w_f, wtf_f, 96);
        else if (i < 163) wt_frag_body((i - 122) * 256 + tid, w_out, wtf_o, 96);
        else              to_xs_pad_body((i - 163) * 256 + tid, x, xs);
    }
    __threadfence();
    grid.sync();

    // ---- stage 1: conv_in (1368) + conv_f (1368), 2736 items
    for (int i = blockIdx.x; i < 2736; i += nb) {
        if (i < 1368)
            conv_body<192, 4, 1>(i, xs, wtf_in, b_in, xpk, xpv, nullptr, nullptr);
        else
            conv_body<96, 2, 2>(i - 1368, xs, wtf_f, b_f, fq4, nullptr, lsc, lrlsc);
    }
    __threadfence();
    grid.sync();

    // ---- stage 2: axial_row (960) + win_attn (4608) + zero_border (4)
    for (int i = blockIdx.x; i < 5572; i += nb)
        attn_body(i, fq4, xpk, xpv, lsc, lrlsc, ys, v1, sm);
    __threadfence();
    grid.sync();

    // ---- stage 3: axial_col, 960 items
    for (int i = blockIdx.x; i < 960; i += nb)
        axial_col_body(i, xpk + 64 * PP, fq4 + 64 * PP, v1, lrlsc, ys, sm);
    __threadfence();
    grid.sync();

    // ---- stage 4: conv_out, 1368 items
    for (int i = blockIdx.x; i < 1368; i += nb)
        conv_body<96, 2, 0>(i, ys, wtf_o, b_out, out, nullptr, nullptr, nullptr);
}

// ---------------------------------------------------------------------------
// Single cooperative launch. Grid = min-occupancy query x 256 CUs (static,
// computed once) so all blocks are co-resident (grid.sync requirement).
// ---------------------------------------------------------------------------
extern "C" void kernel_launch(void* const* d_in, const int* in_sizes, int n_in,
                              void* d_out, int out_size, void* d_ws, size_t ws_size,
                              hipStream_t stream)
{
    const float* x     = (const float*)d_in[0];
    const float* w_in  = (const float*)d_in[1];
    const float* b_in  = (const float*)d_in[2];
    const float* w_f   = (const float*)d_in[3];
    const float* b_f   = (const float*)d_in[4];
    const float* w_out = (const float*)d_in[5];
    const float* b_out = (const float*)d_in[6];
    const float* lsc   = (const float*)d_in[7];
    const float* lrlsc = (const float*)d_in[8];
    float* out = (float*)d_out;
    float* ws  = (float*)d_ws;

    static int ncoop = 0;
    if (ncoop == 0) {
        int nbpc = 0;
        if (hipOccupancyMaxActiveBlocksPerMultiprocessor(&nbpc, mega, 256, 0)
                != hipSuccess || nbpc < 1)
            nbpc = 4;
        if (nbpc > 8) nbpc = 8;
        ncoop = nbpc * 256;            // 256 CUs on MI355X
    }

    void* args[] = {
        (void*)&x, (void*)&w_in, (void*)&b_in, (void*)&w_f, (void*)&b_f,
        (void*)&w_out, (void*)&b_out, (void*)&lsc, (void*)&lrlsc,
        (void*)&out, (void*)&ws
    };
    hipLaunchCooperativeKernel(mega, dim3(ncoop), dim3(256), args, 0, stream);
}

// Round 11
// 261.178 us; speedup vs baseline: 3.0702x; 3.0702x over previous
//
#include <hip/hip_runtime.h>
#include <math.h>

#define HH 240
#define WW 240
#define PP (HH * WW)
#define PW 242              // padded height/width for conv input
#define LOG_MAX_C 4.605170185988091f  // log(100)
#define LOG2E 1.442695040888963f

typedef __bf16 bf16x8 __attribute__((ext_vector_type(8)));
typedef float  f32x4  __attribute__((ext_vector_type(4)));

// native v_exp_f32 (2^x) — NOT __exp2f (glibc macro collision on gfx950 build)
#define EXP2F(x) __builtin_amdgcn_exp2f(x)

// ===========================================================================
// Layouts:
//  xs  [row][icb][px][32]      bf16  — conv B-fragment native (r7-verified)
//  wtf [tap][ocb][icb][512]    bf16  — conv A-fragment native
//  xpk [b*8+h][y][x][4]        fp32  — conv_in K output, PRE-NORMALIZED k-hat
//  xpv [b*8+h][y][x][4]        fp32  — conv_in V output (raw)
//  fq4 [b*8+h][y][x][4]        fp32  — conv_f Q output, PRE-SCALED
//  v1      [h][y][x][4]        fp32  — axial_row output, in d_out scratch
// History:
//  r10-r12: axial restructures -> ~43 us each. r11 KEPT: conv-epilogue
//       pre-norm K / pre-scale Q (win_attn/axials consume directly).
//  r13-r16: four conv experiments (XCD swizzle, B-in-LDS, fat blocks,
//       tri-buffer) all neutral-or-worse. Conv r3 body frozen.
//  r17: launch fusion 10 -> 6: 293 -> 265.6 us.
//  r18: transpose3 deleted (axial_col stages strided): 265.6 -> 257.1 us.
//  r19: cooperative mega-kernel FAILED 4x (802 us): __threadfence+grid.sync
//       between stages forces HBM writeback/refetch of the ~66 MB of
//       intermediates that separate launches keep L2/L3-warm (FETCH 45 ->
//       100-180 MB, HBM throttled at 232 GB/s). Persistent grid-stride also
//       serializes items within a block and halves residency. On multi-XCD
//       CDNA, grid-sync'd persistence pays a coherence tax >> launch
//       overhead for cache-resident intermediates. REVERTED to r18.
// ===========================================================================

// ---------------- prep bodies ----------------------------------------------
__device__ __forceinline__ void to_xs_pad_body(
    int p, const float* __restrict__ in, __bf16* __restrict__ xs)
{
    if (p >= PW * PW) return;
    const int row = p / PW, px = p % PW;
    const bool border = (row == 0 || row == PW - 1 || px == 0 || px == PW - 1);
    union { __bf16 h[32]; uint4 u[4]; } pk;
#pragma unroll
    for (int icb = 0; icb < 3; ++icb) {
        uint4* op = (uint4*)(xs + (((size_t)row * 3 + icb) * PW + px) * 32);
        if (border) {
#pragma unroll
            for (int b = 0; b < 4; ++b) op[b] = make_uint4(0, 0, 0, 0);
        } else {
            const float* ip = in + (size_t)(icb * 32) * PP + (row - 1) * WW + (px - 1);
#pragma unroll
            for (int j = 0; j < 32; ++j) pk.h[j] = (__bf16)ip[(size_t)j * PP];
#pragma unroll
            for (int b = 0; b < 4; ++b) op[b] = pk.u[b];
        }
    }
}

__device__ __forceinline__ void wt_frag_body(
    int t, const float* __restrict__ w, __bf16* __restrict__ wtf, int OC)
{
    if (t >= 9 * (OC / 16) * 3 * 64) return;
    const int lane = t & 63;
    const int rest = t >> 6;
    const int icb  = rest % 3;
    const int to   = rest / 3;
    const int ocb  = to % (OC / 16);
    const int tap  = to / (OC / 16);
    const int ln = lane & 15, quad = lane >> 4;
    const int oc  = ocb * 16 + ln;
    const int ic0 = icb * 32 + quad * 8;
    __bf16* op = wtf + (size_t)rest * 512 + lane * 8;
#pragma unroll
    for (int d = 0; d < 8; ++d)
        op[d] = (__bf16)w[(size_t)(oc * 96 + ic0 + d) * 9 + tap];
}

// prep: [0,81) wt_frag_in | [81,122) wt_frag_f | [122,163) wt_frag_o |
//       [163,392) to_xs_pad
__global__ __launch_bounds__(256) void prep_kernel(
    const float* __restrict__ x, const float* __restrict__ w_in,
    const float* __restrict__ w_f, const float* __restrict__ w_out,
    __bf16* __restrict__ xs, __bf16* __restrict__ wtf_in,
    __bf16* __restrict__ wtf_f, __bf16* __restrict__ wtf_o)
{
    const int bid = blockIdx.x, tid = threadIdx.x;
    if (bid < 81)       wt_frag_body(bid * 256 + tid, w_in, wtf_in, 192);
    else if (bid < 122) wt_frag_body((bid - 81) * 256 + tid, w_f, wtf_f, 96);
    else if (bid < 163) wt_frag_body((bid - 122) * 256 + tid, w_out, wtf_o, 96);
    else                to_xs_pad_body((bid - 163) * 256 + tid, x, xs);
}

// ---------------- conv body (exact r3 form, best measured 43.6 us) ---------
// EPI: 0 = NCHW fp32 | 1 = xpk(k-hat)/xpv | 2 = fq4 (q-hat*scale*LOG2E)
template <int OC, int MT, int EPI>
__device__ __forceinline__ void conv_body(
    int bid, const __bf16* __restrict__ xs, const __bf16* __restrict__ wtf,
    const float* __restrict__ bias, float* __restrict__ out0,
    float* __restrict__ out1, const float* __restrict__ lsc,
    const float* __restrict__ lrlsc)
{
    const int group = bid / 24;
    const int w24   = bid % 24;
    const int z     = w24 >> 3;
    const int xy    = group * 8 + (w24 & 7);
    if (xy >= 450) return;
    const int x0  = (xy % 15) * 16;
    const int y0  = (xy / 15) * 8;
    const int oc0 = z * (MT * 16);
    const int ocb0 = oc0 / 16;

    const int wave = threadIdx.x >> 6;
    const int lane = threadIdx.x & 63;
    const int ln   = lane & 15;
    const int quad = lane >> 4;
    const int r0   = y0 + wave * 2;

    f32x4 acc[MT][2] = {};
    bf16x8 a[2][MT], b[2][2];

    const __bf16* abase = wtf + (size_t)lane * 8;
    const __bf16* bbase = xs + (size_t)ln * 32 + quad * 8;

#define LOAD_CHUNK(c, buf)                                                    \
    {                                                                         \
        const int tap_ = (c) / 3, icb_ = (c) % 3;                             \
        const int dy_ = tap_ / 3, dx_ = tap_ % 3;                             \
        const __bf16* ap_ = abase + (size_t)((tap_ * (OC / 16) + ocb0) * 3 + icb_) * 512; \
        _Pragma("unroll")                                                     \
        for (int mi = 0; mi < MT; ++mi)                                       \
            a[buf][mi] = *(const bf16x8*)(ap_ + (size_t)mi * 1536);           \
        _Pragma("unroll")                                                     \
        for (int ni = 0; ni < 2; ++ni)                                        \
            b[buf][ni] = *(const bf16x8*)(bbase +                             \
                (((size_t)(r0 + ni + dy_) * 3 + icb_) * PW + x0 + dx_) * 32); \
    }

    LOAD_CHUNK(0, 0)
#pragma unroll
    for (int c = 0; c < 27; ++c) {
        const int cur = c & 1, nxt = cur ^ 1;
        if (c < 26) LOAD_CHUNK(c + 1, nxt)
#pragma unroll
        for (int mi = 0; mi < MT; ++mi)
#pragma unroll
            for (int ni = 0; ni < 2; ++ni)
                acc[mi][ni] = __builtin_amdgcn_mfma_f32_16x16x32_bf16(
                    a[cur][mi], b[cur][ni], acc[mi][ni], 0, 0, 0);
    }
#undef LOAD_CHUNK

    if constexpr (EPI == 0) {
#pragma unroll
        for (int mi = 0; mi < MT; ++mi) {
#pragma unroll
            for (int r = 0; r < 4; ++r) {
                const int oc = oc0 + mi * 16 + quad * 4 + r;
                const float bv = bias[oc];
#pragma unroll
                for (int ni = 0; ni < 2; ++ni)
                    out0[(size_t)oc * PP + (r0 + ni) * WW + x0 + ln] = acc[mi][ni][r] + bv;
            }
        }
    } else if constexpr (EPI == 1) {
#pragma unroll
        for (int mi = 0; mi < MT; ++mi) {
            const f32x4 bv = *(const f32x4*)(bias + oc0 + mi * 16 + quad * 4);
            float* dst = (mi >> 1) ? out1 : out0;
            const int h8 = z * 8 + (mi & 1) * 4 + quad;
#pragma unroll
            for (int ni = 0; ni < 2; ++ni) {
                f32x4 o = acc[mi][ni] + bv;
                if ((mi >> 1) == 0) {  // K side: store k-hat
                    const float ksq = o[0]*o[0] + o[1]*o[1] + o[2]*o[2] + o[3]*o[3];
                    o *= 1.0f / fmaxf(sqrtf(ksq), 1e-12f);
                }
                *(f32x4*)(dst + (((size_t)h8 * 240 + r0 + ni) * 240 + x0 + ln) * 4) = o;
            }
        }
    } else {
#pragma unroll
        for (int mi = 0; mi < MT; ++mi) {
            const f32x4 bv = *(const f32x4*)(bias + oc0 + mi * 16 + quad * 4);
            const int h8 = z * 8 + mi * 4 + quad;
            const int br = h8 >> 3, hh = h8 & 7;
            const float ls = (br == 2) ? lrlsc[hh] : lsc[hh];
            const float qsc = __expf(fminf(ls, LOG_MAX_C)) * LOG2E;
#pragma unroll
            for (int ni = 0; ni < 2; ++ni) {
                f32x4 o = acc[mi][ni] + bv;
                const float qsq = o[0]*o[0] + o[1]*o[1] + o[2]*o[2] + o[3]*o[3];
                o *= qsc / fmaxf(sqrtf(qsq), 1e-12f);
                *(f32x4*)(out0 + (((size_t)h8 * 240 + r0 + ni) * 240 + x0 + ln) * 4) = o;
            }
        }
    }
}

// conv_in (1368 blocks) + conv_f (1368 blocks) fused: disjoint outputs,
// same xs input; conv_f backfills CUs while conv_in drains.
__global__ __launch_bounds__(256) void conv_in_f(
    const __bf16* __restrict__ xs, const __bf16* __restrict__ wtf_in,
    const __bf16* __restrict__ wtf_f, const float* __restrict__ b_in,
    const float* __restrict__ b_f, float* __restrict__ xpk,
    float* __restrict__ xpv, float* __restrict__ fq4,
    const float* __restrict__ lsc, const float* __restrict__ lrlsc)
{
    const int bid = blockIdx.x;
    if (bid < 1368)
        conv_body<192, 4, 1>(bid, xs, wtf_in, b_in, xpk, xpv, nullptr, nullptr);
    else
        conv_body<96, 2, 2>(bid - 1368, xs, wtf_f, b_f, fq4, nullptr, lsc, lrlsc);
}

__global__ __launch_bounds__(256) void conv_out_k(
    const __bf16* __restrict__ ys, const __bf16* __restrict__ wtf_o,
    const float* __restrict__ b_out, float* __restrict__ out)
{
    conv_body<96, 2, 0>(blockIdx.x, ys, wtf_o, b_out, out, nullptr, nullptr, nullptr);
}

// ---------------- fused attention stage ------------------------------------
// [0,960): axial_row (long blocks, dispatched first)
// [960,5568): win_attn branches 0+1 (short blocks, backfill)
// [5568,5572): zero_border of ys
// axial_row writes ONLY v1 (= d_out scratch); win_attn reads xpk/xpv/fq4
// b0/b1 and writes ys interior; zero_border writes ys border. No overlap.
__global__ __launch_bounds__(256) void attn_row_fused(
    const float* __restrict__ fq4, const float* __restrict__ xpk,
    const float* __restrict__ xpv, const float* __restrict__ lsc,
    const float* __restrict__ lrlsc, __bf16* __restrict__ ys,
    float* __restrict__ v1)
{
    __shared__ f32x4 sm[960];
    const int bid = blockIdx.x;
    const int t = threadIdx.x;

    if (bid < 960) {
        // ---- axial_row: 2 rows/block, 2 queries/thread (r12 structure)
        const int bx = bid >> 3, h = bid & 7;
        const int half = t >> 7, tl = t & 127;
        const int y = bx * 2 + half;
        f32x4* ks = sm;            // [2][240]
        f32x4* vs = sm + 480;      // [2][240]

        const float scale = __expf(fminf(lrlsc[h], LOG_MAX_C));
        const float negM2 = -scale * LOG2E;
        const size_t rowb = ((size_t)h * 240 + y) * 240;
        const float* fq4b = fq4 + 64 * PP;
        const float* xpkb = xpk + 64 * PP;
        const float* xpvb = xpv + 64 * PP;
        f32x4 qreg[2] = {};

        if (tl < 120) {
#pragma unroll
            for (int s = 0; s < 2; ++s) {
                const int i = tl + s * 120;
                const size_t p4 = (rowb + i) * 4;
                ks[half * 240 + i] = *(const f32x4*)(xpkb + p4);
                vs[half * 240 + i] = *(const f32x4*)(xpvb + p4);
                qreg[s] = *(const f32x4*)(fq4b + p4);
            }
        }
        __syncthreads();
        if (tl < 120) {
            float l0 = 0.f, l1 = 0.f;
            f32x4 a0 = {0, 0, 0, 0}, a1 = {0, 0, 0, 0};
#pragma unroll 4
            for (int j = 0; j < 240; ++j) {
                const f32x4 kk = ks[half * 240 + j];
                const f32x4 vv = vs[half * 240 + j];
                const float s0 = fmaf(qreg[0][0], kk[0],
                                 fmaf(qreg[0][1], kk[1],
                                 fmaf(qreg[0][2], kk[2],
                                 fmaf(qreg[0][3], kk[3], negM2))));
                const float s1 = fmaf(qreg[1][0], kk[0],
                                 fmaf(qreg[1][1], kk[1],
                                 fmaf(qreg[1][2], kk[2],
                                 fmaf(qreg[1][3], kk[3], negM2))));
                const float p0 = EXP2F(s0);
                const float p1 = EXP2F(s1);
                l0 += p0; l1 += p1;
                a0 += vv * p0;
                a1 += vv * p1;
            }
            *(f32x4*)(v1 + (rowb + tl) * 4) = a0 * (1.0f / l0);
            *(f32x4*)(v1 + (rowb + tl + 120) * 4) = a1 * (1.0f / l1);
        }
    } else if (bid < 5568) {
        // ---- win_attn branches 0+1 (r11 pre-scaled inputs)
        const int id2 = bid - 960;
        const int br  = id2 / 2304;          // 0: plain, 1: shifted
        const int id  = id2 % 2304;
        const int wi  = id / 288;
        const int g   = id % 288;
        const int wy  = g / 6;
        const int wx  = (g % 6) * 8 + wi;
        const int gshift = br * 3, sshift = br * 2;
        const size_t choff = (size_t)br * 32 * PP;
        const int h = t / 25, i = t % 25;
        f32x4* ks = sm;            // [8][25]
        f32x4* vs = sm + 200;      // [8][25]
        f32x4 qn = {0, 0, 0, 0};
        float negM2 = 0.f;
        int oy = 0, ox = 0;

        if (t < 200) {
            const int y = (wy * 5 + i / 5 + gshift) % HH;
            const int x = (wx * 5 + i % 5 + gshift) % WW;
            const size_t p4 = choff + (((size_t)h * 240 + y) * 240 + x) * 4;
            qn = *(const f32x4*)(fq4 + p4);              // pre-scaled q
            ks[h * 25 + i] = *(const f32x4*)(xpk + p4);  // pre-normalized k
            vs[h * 25 + i] = *(const f32x4*)(xpv + p4);
            const float scale = __expf(fminf(lsc[h], LOG_MAX_C));
            negM2 = -scale * LOG2E;
            oy = (wy * 5 + i / 5 + sshift) % HH;
            ox = (wx * 5 + i % 5 + sshift) % WW;
        }
        __syncthreads();
        if (t < 200) {
            float l = 0.f;
            f32x4 acc = {0, 0, 0, 0};
#pragma unroll
            for (int j = 0; j < 25; ++j) {
                const f32x4 kk = ks[h * 25 + j];
                const float s = fmaf(qn[0], kk[0],
                                fmaf(qn[1], kk[1],
                                fmaf(qn[2], kk[2],
                                fmaf(qn[3], kk[3], negM2))));
                const float p = EXP2F(s);
                l += p;
                acc += vs[h * 25 + j] * p;
            }
            const float linv = 1.0f / l;
            union { __bf16 h4[4]; uint2 u; } o;
#pragma unroll
            for (int d = 0; d < 4; ++d) o.h4[d] = (__bf16)(acc[d] * linv);
            *(uint2*)(ys + (((size_t)(oy + 1) * 3 + br) * PW + ox + 1) * 32 + h * 4) = o.u;
        }
    } else {
        // ---- zero_border of ys
        const int idx = (bid - 5568) * 256 + t;
        if (idx >= 4 * PW) return;
        const int g = idx / PW, i = idx % PW;
        int row, px;
        if (g == 0)      { row = 0;      px = i; }
        else if (g == 1) { row = PW - 1; px = i; }
        else if (g == 2) { row = i;      px = 0; }
        else             { row = i;      px = PW - 1; }
#pragma unroll
        for (int icb = 0; icb < 3; ++icb) {
            uint4* op = (uint4*)(ys + (((size_t)row * 3 + icb) * PW + px) * 32);
#pragma unroll
            for (int b = 0; b < 4; ++b) op[b] = make_uint4(0, 0, 0, 0);
        }
    }
}

// ---------------------------------------------------------------------------
// Axial column attention (over h). r18: stages DIRECTLY from natural-layout
// kn (= xpk b2, k-hat), qn (= fq4 b2, pre-scaled) and v1 with y-strided
// f32x4 reads (stride 3840 B). L2 absorbs the line overfetch (~23 KB/block).
// Compute loop identical to r12. Writes ys branch-2 interior.
// ---------------------------------------------------------------------------
__global__ __launch_bounds__(256) void axial_col_kernel(
    const float* __restrict__ knb, const float* __restrict__ qnb,
    const float* __restrict__ v1b, const float* __restrict__ lsc,
    __bf16* __restrict__ ys)
{
    __shared__ f32x4 ks[2][240];
    __shared__ f32x4 vs[2][240];
    const int bid = blockIdx.x;
    const int wi  = bid / 120;           // 0..7
    const int g   = bid % 120;
    const int h   = g % 8;
    const int xc  = g / 8;               // 0..14
    const int t = threadIdx.x;
    const int half = t >> 7, tl = t & 127;
    const int x = xc * 16 + wi * 2 + half;

    const float scale = __expf(fminf(lsc[h], LOG_MAX_C));
    const float negM2 = -scale * LOG2E;
    const size_t hb = (size_t)h * 240;
    f32x4 qreg[2] = {};

    if (tl < 120) {
#pragma unroll
        for (int s = 0; s < 2; ++s) {
            const int i = tl + s * 120;          // y position
            const size_t p4 = ((hb + i) * 240 + x) * 4;
            ks[half][i] = *(const f32x4*)(knb + p4);
            vs[half][i] = *(const f32x4*)(v1b + p4);
            qreg[s] = *(const f32x4*)(qnb + p4);
        }
    }
    __syncthreads();
    if (tl < 120) {
        float l0 = 0.f, l1 = 0.f;
        f32x4 a0 = {0, 0, 0, 0}, a1 = {0, 0, 0, 0};
#pragma unroll 4
        for (int j = 0; j < 240; ++j) {
            const f32x4 kk = ks[half][j];
            const f32x4 vv = vs[half][j];
            const float s0 = fmaf(qreg[0][0], kk[0],
                             fmaf(qreg[0][1], kk[1],
                             fmaf(qreg[0][2], kk[2],
                             fmaf(qreg[0][3], kk[3], negM2))));
            const float s1 = fmaf(qreg[1][0], kk[0],
                             fmaf(qreg[1][1], kk[1],
                             fmaf(qreg[1][2], kk[2],
                             fmaf(qreg[1][3], kk[3], negM2))));
            const float p0 = EXP2F(s0);
            const float p1 = EXP2F(s1);
            l0 += p0; l1 += p1;
            a0 += vv * p0;
            a1 += vv * p1;
        }
#pragma unroll
        for (int s = 0; s < 2; ++s) {
            const f32x4 o4 = s ? a1 * (1.0f / l1) : a0 * (1.0f / l0);
            const int i = tl + s * 120;
            union { __bf16 h4[4]; uint2 u; } o;
#pragma unroll
            for (int d = 0; d < 4; ++d) o.h4[d] = (__bf16)o4[d];
            *(uint2*)(ys + (((size_t)(i + 1) * 3 + 2) * PW + x + 1) * 32 + h * 4) = o.u;
        }
    }
}

// ---------------------------------------------------------------------------
// Pipeline (5 launches). Workspace (fp32 units):
//   xpk 96PP | xpv 96PP | fq4 96PP | xs/ys bf16 | wtf_in | wtf_f | wtf_o
// v1 lives in d_out (dead until conv_out; 32PP <= 96PP).
// axial_col reads xpk b2 / fq4 b2 / v1 directly (no transpose buffers).
// ---------------------------------------------------------------------------
extern "C" void kernel_launch(void* const* d_in, const int* in_sizes, int n_in,
                              void* d_out, int out_size, void* d_ws, size_t ws_size,
                              hipStream_t stream)
{
    const float* x     = (const float*)d_in[0];
    const float* w_in  = (const float*)d_in[1];
    const float* b_in  = (const float*)d_in[2];
    const float* w_f   = (const float*)d_in[3];
    const float* b_f   = (const float*)d_in[4];
    const float* w_out = (const float*)d_in[5];
    const float* b_out = (const float*)d_in[6];
    const float* lsc   = (const float*)d_in[7];
    const float* lrlsc = (const float*)d_in[8];
    float* out = (float*)d_out;

    float* ws  = (float*)d_ws;
    float* xpk = ws;                   // 96*PP
    float* xpv = xpk + 96 * PP;        // 96*PP
    float* fq4 = xpv + 96 * PP;        // 96*PP
    __bf16* xs     = (__bf16*)(fq4 + 96 * PP);            // 242*3*242*32 bf16
    __bf16* wtf_in = xs + (size_t)PW * 3 * PW * 32;
    __bf16* wtf_f  = wtf_in + 9 * 12 * 3 * 512;
    __bf16* wtf_o  = wtf_f + 9 * 6 * 3 * 512;
    __bf16* ys     = xs;               // alias: xs dead after conv_in_f

    float* v1  = out;                  // d_out scratch, dead until conv_out

    prep_kernel<<<392, 256, 0, stream>>>(x, w_in, w_f, w_out,
                                         xs, wtf_in, wtf_f, wtf_o);

    conv_in_f<<<2736, 256, 0, stream>>>(xs, wtf_in, wtf_f, b_in, b_f,
                                        xpk, xpv, fq4, lsc, lrlsc);

    attn_row_fused<<<5572, 256, 0, stream>>>(fq4, xpk, xpv, lsc, lrlsc, ys, v1);

    axial_col_kernel<<<960, 256, 0, stream>>>(
        xpk + 64 * PP, fq4 + 64 * PP, v1, lrlsc, ys);

    conv_out_k<<<1368, 256, 0, stream>>>(ys, wtf_o, b_out, out);
}

// Round 13
// 230.872 us; speedup vs baseline: 3.4732x; 1.1313x over previous
//
#include <hip/hip_runtime.h>
#include <math.h>

#define HH 240
#define WW 240
#define PP (HH * WW)
#define PW 242              // padded height/width for conv input
#define LOG_MAX_C 4.605170185988091f  // log(100)
#define LOG2E 1.442695040888963f

typedef __bf16 bf16x8 __attribute__((ext_vector_type(8)));
typedef float  f32x4  __attribute__((ext_vector_type(4)));

// native v_exp_f32 (2^x) — NOT __exp2f (glibc macro collision on gfx950 build)
#define EXP2F(x) __builtin_amdgcn_exp2f(x)

// ===========================================================================
// Layouts:
//  xs  [row][icb][px][32]      bf16  — conv B-fragment native (r7-verified)
//  wtf [tap][ocb][icb][512]    bf16  — conv A-fragment native
//  xpk [b*8+h][y][x][4]        fp32  — conv_in K output, PRE-NORMALIZED k-hat
//  xpv [b*8+h][y][x][4]        fp32  — conv_in V output (raw)
//  fq4 [b*8+h][y][x][4]        fp32  — conv_f Q output, PRE-SCALED
//  v1      [h][y][x][4]        fp32  — axial_row output, in d_out scratch
// History:
//  r10-r12: axial restructures -> ~43 us each. r11 KEPT: conv-epilogue
//       pre-norm K / pre-scale Q (win_attn/axials consume directly).
//  r13-r16: four conv experiments (XCD swizzle, B-in-LDS, fat blocks,
//       tri-buffer) all neutral-or-worse; retrospectively ALL consistent
//       with an L2-aggregate-BW bound (~23 TB/s ~= 65% of 34.5 ceiling,
//       99% of 1.46 GB conv traffic is cache-served).
//  r17: launch fusion 10 -> 6: 293 -> 265.6 us.
//  r18: transpose3 deleted: 265.6 -> 257.1 us (reproduced r20: 261.2).
//  r19: cooperative mega-kernel FAILED (802 us): grid.sync coherence tax
//       forces HBM writeback/refetch of L2/L3-warm intermediates.
//  r21: conv A-DEDUP via LDS, occupancy-preserving (the one untried cell:
//       cut traffic AND hold occupancy). All 4 waves/block loaded IDENTICAL
//       A frags (583 MB of 1.46 GB redundant). Wave w stages frag w of
//       chunk c+1 into 8 KB dbuf LDS; staged 2-AHEAD so the barrier's
//       mandatory vmcnt(0) drain IS the sync (no mid-iter waits).
//       1 barrier/chunk, B path unchanged, grid/waves/epilogue unchanged.
//       Traffic 1.46 -> 0.95 GB. Predict conv_in_f 63 -> ~47 us if L2-BW
//       theory right; revert if >=5% regression (latency-bound confirmed).
//       (r12 submission had an 8-arg call typo; this is the fixed build.)
// ===========================================================================

// ---------------- prep bodies ----------------------------------------------
__device__ __forceinline__ void to_xs_pad_body(
    int p, const float* __restrict__ in, __bf16* __restrict__ xs)
{
    if (p >= PW * PW) return;
    const int row = p / PW, px = p % PW;
    const bool border = (row == 0 || row == PW - 1 || px == 0 || px == PW - 1);
    union { __bf16 h[32]; uint4 u[4]; } pk;
#pragma unroll
    for (int icb = 0; icb < 3; ++icb) {
        uint4* op = (uint4*)(xs + (((size_t)row * 3 + icb) * PW + px) * 32);
        if (border) {
#pragma unroll
            for (int b = 0; b < 4; ++b) op[b] = make_uint4(0, 0, 0, 0);
        } else {
            const float* ip = in + (size_t)(icb * 32) * PP + (row - 1) * WW + (px - 1);
#pragma unroll
            for (int j = 0; j < 32; ++j) pk.h[j] = (__bf16)ip[(size_t)j * PP];
#pragma unroll
            for (int b = 0; b < 4; ++b) op[b] = pk.u[b];
        }
    }
}

__device__ __forceinline__ void wt_frag_body(
    int t, const float* __restrict__ w, __bf16* __restrict__ wtf, int OC)
{
    if (t >= 9 * (OC / 16) * 3 * 64) return;
    const int lane = t & 63;
    const int rest = t >> 6;
    const int icb  = rest % 3;
    const int to   = rest / 3;
    const int ocb  = to % (OC / 16);
    const int tap  = to / (OC / 16);
    const int ln = lane & 15, quad = lane >> 4;
    const int oc  = ocb * 16 + ln;
    const int ic0 = icb * 32 + quad * 8;
    __bf16* op = wtf + (size_t)rest * 512 + lane * 8;
#pragma unroll
    for (int d = 0; d < 8; ++d)
        op[d] = (__bf16)w[(size_t)(oc * 96 + ic0 + d) * 9 + tap];
}

// prep: [0,81) wt_frag_in | [81,122) wt_frag_f | [122,163) wt_frag_o |
//       [163,392) to_xs_pad
__global__ __launch_bounds__(256) void prep_kernel(
    const float* __restrict__ x, const float* __restrict__ w_in,
    const float* __restrict__ w_f, const float* __restrict__ w_out,
    __bf16* __restrict__ xs, __bf16* __restrict__ wtf_in,
    __bf16* __restrict__ wtf_f, __bf16* __restrict__ wtf_o)
{
    const int bid = blockIdx.x, tid = threadIdx.x;
    if (bid < 81)       wt_frag_body(bid * 256 + tid, w_in, wtf_in, 192);
    else if (bid < 122) wt_frag_body((bid - 81) * 256 + tid, w_f, wtf_f, 96);
    else if (bid < 163) wt_frag_body((bid - 122) * 256 + tid, w_out, wtf_o, 96);
    else                to_xs_pad_body((bid - 163) * 256 + tid, x, xs);
}

// ---------------- conv body (r3 grid/frag math + r21 LDS A-dedup) ----------
// EPI: 0 = NCHW fp32 | 1 = xpk(k-hat)/xpv | 2 = fq4 (q-hat*scale*LOG2E)
// As: 2 * MT * 512 bf16 pool ([buf][frag][lane*8]). Wave w stages frag w of
// chunk c+1 (loaded at iter c-1, so the barrier's vmcnt drain covers it).
template <int OC, int MT, int EPI>
__device__ __forceinline__ void conv_body(
    int bid, const __bf16* __restrict__ xs, const __bf16* __restrict__ wtf,
    const float* __restrict__ bias, float* __restrict__ out0,
    float* __restrict__ out1, const float* __restrict__ lsc,
    const float* __restrict__ lrlsc, __bf16* As)
{
    const int group = bid / 24;
    const int w24   = bid % 24;
    const int z     = w24 >> 3;
    const int xy    = group * 8 + (w24 & 7);
    if (xy >= 450) return;      // block-uniform, before any barrier
    const int x0  = (xy % 15) * 16;
    const int y0  = (xy / 15) * 8;
    const int oc0 = z * (MT * 16);
    const int ocb0 = oc0 / 16;

    const int wave = threadIdx.x >> 6;
    const int lane = threadIdx.x & 63;
    const int ln   = lane & 15;
    const int quad = lane >> 4;
    const int r0   = y0 + wave * 2;

    f32x4 acc[MT][2] = {};
    bf16x8 a[MT], b[2][2], astg;

    const __bf16* abase = wtf + (size_t)lane * 8;
    const __bf16* bbase = xs + (size_t)ln * 32 + quad * 8;

    // A source for the frag THIS wave stages (frag index == wave):
    //   original addr = abase + ((tap*(OC/16)+ocb0)*3+icb)*512 + mi*1536
    //                 = abase + (((tap*(OC/16)) + ocb0 + mi)*3 + icb)*512
#define ASRC(c) (abase + ((size_t)(((c) / 3) * (OC / 16) + ocb0 + wave) * 3 + (c) % 3) * 512)
#define BLOAD(c, buf)                                                         \
    {                                                                         \
        const int tap_ = (c) / 3, icb_ = (c) % 3;                             \
        const int dy_ = tap_ / 3, dx_ = tap_ % 3;                             \
        _Pragma("unroll")                                                     \
        for (int ni = 0; ni < 2; ++ni)                                        \
            b[buf][ni] = *(const bf16x8*)(bbase +                             \
                (((size_t)(r0 + ni + dy_) * 3 + icb_) * PW + x0 + dx_) * 32); \
    }

    // ---- prolog: As[0] <- A(0); astg <- A(1); B(0) in flight
    if (wave < MT) {
        astg = *(const bf16x8*)ASRC(0);
        *(bf16x8*)(As + (size_t)wave * 512 + lane * 8) = astg;   // buf0
        astg = *(const bf16x8*)ASRC(1);
    }
    BLOAD(0, 0)

#pragma unroll
    for (int c = 0; c < 27; ++c) {
        const int cur = c & 1, nxt = cur ^ 1;
        // barrier drains vmcnt (b[cur], astg=A(c+1)) + lgkm; As[cur] visible.
        __syncthreads();
        if (c < 26 && wave < MT)
            *(bf16x8*)(As + ((size_t)(nxt * MT) + wave) * 512 + lane * 8) = astg;
#pragma unroll
        for (int mi = 0; mi < MT; ++mi)
            a[mi] = *(const bf16x8*)(As + ((size_t)(cur * MT) + mi) * 512 + lane * 8);
        if (c < 25 && wave < MT)
            astg = *(const bf16x8*)ASRC(c + 2);
        if (c < 26) BLOAD(c + 1, nxt)
#pragma unroll
        for (int mi = 0; mi < MT; ++mi)
#pragma unroll
            for (int ni = 0; ni < 2; ++ni)
                acc[mi][ni] = __builtin_amdgcn_mfma_f32_16x16x32_bf16(
                    a[mi], b[cur][ni], acc[mi][ni], 0, 0, 0);
    }
#undef ASRC
#undef BLOAD

    if constexpr (EPI == 0) {
#pragma unroll
        for (int mi = 0; mi < MT; ++mi) {
#pragma unroll
            for (int r = 0; r < 4; ++r) {
                const int oc = oc0 + mi * 16 + quad * 4 + r;
                const float bv = bias[oc];
#pragma unroll
                for (int ni = 0; ni < 2; ++ni)
                    out0[(size_t)oc * PP + (r0 + ni) * WW + x0 + ln] = acc[mi][ni][r] + bv;
            }
        }
    } else if constexpr (EPI == 1) {
#pragma unroll
        for (int mi = 0; mi < MT; ++mi) {
            const f32x4 bv = *(const f32x4*)(bias + oc0 + mi * 16 + quad * 4);
            float* dst = (mi >> 1) ? out1 : out0;
            const int h8 = z * 8 + (mi & 1) * 4 + quad;
#pragma unroll
            for (int ni = 0; ni < 2; ++ni) {
                f32x4 o = acc[mi][ni] + bv;
                if ((mi >> 1) == 0) {  // K side: store k-hat
                    const float ksq = o[0]*o[0] + o[1]*o[1] + o[2]*o[2] + o[3]*o[3];
                    o *= 1.0f / fmaxf(sqrtf(ksq), 1e-12f);
                }
                *(f32x4*)(dst + (((size_t)h8 * 240 + r0 + ni) * 240 + x0 + ln) * 4) = o;
            }
        }
    } else {
#pragma unroll
        for (int mi = 0; mi < MT; ++mi) {
            const f32x4 bv = *(const f32x4*)(bias + oc0 + mi * 16 + quad * 4);
            const int h8 = z * 8 + mi * 4 + quad;
            const int br = h8 >> 3, hh = h8 & 7;
            const float ls = (br == 2) ? lrlsc[hh] : lsc[hh];
            const float qsc = __expf(fminf(ls, LOG_MAX_C)) * LOG2E;
#pragma unroll
            for (int ni = 0; ni < 2; ++ni) {
                f32x4 o = acc[mi][ni] + bv;
                const float qsq = o[0]*o[0] + o[1]*o[1] + o[2]*o[2] + o[3]*o[3];
                o *= qsc / fmaxf(sqrtf(qsq), 1e-12f);
                *(f32x4*)(out0 + (((size_t)h8 * 240 + r0 + ni) * 240 + x0 + ln) * 4) = o;
            }
        }
    }
}

// conv_in (1368 blocks) + conv_f (1368 blocks) fused: disjoint outputs,
// same xs input; conv_f backfills CUs while conv_in drains.
__global__ __launch_bounds__(256) void conv_in_f(
    const __bf16* __restrict__ xs, const __bf16* __restrict__ wtf_in,
    const __bf16* __restrict__ wtf_f, const float* __restrict__ b_in,
    const float* __restrict__ b_f, float* __restrict__ xpk,
    float* __restrict__ xpv, float* __restrict__ fq4,
    const float* __restrict__ lsc, const float* __restrict__ lrlsc)
{
    __shared__ __bf16 As[2 * 4 * 512];   // 8 KB pool (max MT=4)
    const int bid = blockIdx.x;
    if (bid < 1368)
        conv_body<192, 4, 1>(bid, xs, wtf_in, b_in, xpk, xpv, nullptr, nullptr, As);
    else
        conv_body<96, 2, 2>(bid - 1368, xs, wtf_f, b_f, fq4, nullptr, lsc, lrlsc, As);
}

__global__ __launch_bounds__(256) void conv_out_k(
    const __bf16* __restrict__ ys, const __bf16* __restrict__ wtf_o,
    const float* __restrict__ b_out, float* __restrict__ out)
{
    __shared__ __bf16 As[2 * 2 * 512];   // 4 KB pool (MT=2)
    conv_body<96, 2, 0>(blockIdx.x, ys, wtf_o, b_out, out, nullptr,
                        nullptr, nullptr, As);
}

// ---------------- fused attention stage ------------------------------------
// [0,960): axial_row (long blocks, dispatched first)
// [960,5568): win_attn branches 0+1 (short blocks, backfill)
// [5568,5572): zero_border of ys
// axial_row writes ONLY v1 (= d_out scratch); win_attn reads xpk/xpv/fq4
// b0/b1 and writes ys interior; zero_border writes ys border. No overlap.
__global__ __launch_bounds__(256) void attn_row_fused(
    const float* __restrict__ fq4, const float* __restrict__ xpk,
    const float* __restrict__ xpv, const float* __restrict__ lsc,
    const float* __restrict__ lrlsc, __bf16* __restrict__ ys,
    float* __restrict__ v1)
{
    __shared__ f32x4 sm[960];
    const int bid = blockIdx.x;
    const int t = threadIdx.x;

    if (bid < 960) {
        // ---- axial_row: 2 rows/block, 2 queries/thread (r12 structure)
        const int bx = bid >> 3, h = bid & 7;
        const int half = t >> 7, tl = t & 127;
        const int y = bx * 2 + half;
        f32x4* ks = sm;            // [2][240]
        f32x4* vs = sm + 480;      // [2][240]

        const float scale = __expf(fminf(lrlsc[h], LOG_MAX_C));
        const float negM2 = -scale * LOG2E;
        const size_t rowb = ((size_t)h * 240 + y) * 240;
        const float* fq4b = fq4 + 64 * PP;
        const float* xpkb = xpk + 64 * PP;
        const float* xpvb = xpv + 64 * PP;
        f32x4 qreg[2] = {};

        if (tl < 120) {
#pragma unroll
            for (int s = 0; s < 2; ++s) {
                const int i = tl + s * 120;
                const size_t p4 = (rowb + i) * 4;
                ks[half * 240 + i] = *(const f32x4*)(xpkb + p4);
                vs[half * 240 + i] = *(const f32x4*)(xpvb + p4);
                qreg[s] = *(const f32x4*)(fq4b + p4);
            }
        }
        __syncthreads();
        if (tl < 120) {
            float l0 = 0.f, l1 = 0.f;
            f32x4 a0 = {0, 0, 0, 0}, a1 = {0, 0, 0, 0};
#pragma unroll 4
            for (int j = 0; j < 240; ++j) {
                const f32x4 kk = ks[half * 240 + j];
                const f32x4 vv = vs[half * 240 + j];
                const float s0 = fmaf(qreg[0][0], kk[0],
                                 fmaf(qreg[0][1], kk[1],
                                 fmaf(qreg[0][2], kk[2],
                                 fmaf(qreg[0][3], kk[3], negM2))));
                const float s1 = fmaf(qreg[1][0], kk[0],
                                 fmaf(qreg[1][1], kk[1],
                                 fmaf(qreg[1][2], kk[2],
                                 fmaf(qreg[1][3], kk[3], negM2))));
                const float p0 = EXP2F(s0);
                const float p1 = EXP2F(s1);
                l0 += p0; l1 += p1;
                a0 += vv * p0;
                a1 += vv * p1;
            }
            *(f32x4*)(v1 + (rowb + tl) * 4) = a0 * (1.0f / l0);
            *(f32x4*)(v1 + (rowb + tl + 120) * 4) = a1 * (1.0f / l1);
        }
    } else if (bid < 5568) {
        // ---- win_attn branches 0+1 (r11 pre-scaled inputs)
        const int id2 = bid - 960;
        const int br  = id2 / 2304;          // 0: plain, 1: shifted
        const int id  = id2 % 2304;
        const int wi  = id / 288;
        const int g   = id % 288;
        const int wy  = g / 6;
        const int wx  = (g % 6) * 8 + wi;
        const int gshift = br * 3, sshift = br * 2;
        const size_t choff = (size_t)br * 32 * PP;
        const int h = t / 25, i = t % 25;
        f32x4* ks = sm;            // [8][25]
        f32x4* vs = sm + 200;      // [8][25]
        f32x4 qn = {0, 0, 0, 0};
        float negM2 = 0.f;
        int oy = 0, ox = 0;

        if (t < 200) {
            const int y = (wy * 5 + i / 5 + gshift) % HH;
            const int x = (wx * 5 + i % 5 + gshift) % WW;
            const size_t p4 = choff + (((size_t)h * 240 + y) * 240 + x) * 4;
            qn = *(const f32x4*)(fq4 + p4);              // pre-scaled q
            ks[h * 25 + i] = *(const f32x4*)(xpk + p4);  // pre-normalized k
            vs[h * 25 + i] = *(const f32x4*)(xpv + p4);
            const float scale = __expf(fminf(lsc[h], LOG_MAX_C));
            negM2 = -scale * LOG2E;
            oy = (wy * 5 + i / 5 + sshift) % HH;
            ox = (wx * 5 + i % 5 + sshift) % WW;
        }
        __syncthreads();
        if (t < 200) {
            float l = 0.f;
            f32x4 acc = {0, 0, 0, 0};
#pragma unroll
            for (int j = 0; j < 25; ++j) {
                const f32x4 kk = ks[h * 25 + j];
                const float s = fmaf(qn[0], kk[0],
                                fmaf(qn[1], kk[1],
                                fmaf(qn[2], kk[2],
                                fmaf(qn[3], kk[3], negM2))));
                const float p = EXP2F(s);
                l += p;
                acc += vs[h * 25 + j] * p;
            }
            const float linv = 1.0f / l;
            union { __bf16 h4[4]; uint2 u; } o;
#pragma unroll
            for (int d = 0; d < 4; ++d) o.h4[d] = (__bf16)(acc[d] * linv);
            *(uint2*)(ys + (((size_t)(oy + 1) * 3 + br) * PW + ox + 1) * 32 + h * 4) = o.u;
        }
    } else {
        // ---- zero_border of ys
        const int idx = (bid - 5568) * 256 + t;
        if (idx >= 4 * PW) return;
        const int g = idx / PW, i = idx % PW;
        int row, px;
        if (g == 0)      { row = 0;      px = i; }
        else if (g == 1) { row = PW - 1; px = i; }
        else if (g == 2) { row = i;      px = 0; }
        else             { row = i;      px = PW - 1; }
#pragma unroll
        for (int icb = 0; icb < 3; ++icb) {
            uint4* op = (uint4*)(ys + (((size_t)row * 3 + icb) * PW + px) * 32);
#pragma unroll
            for (int b = 0; b < 4; ++b) op[b] = make_uint4(0, 0, 0, 0);
        }
    }
}

// ---------------------------------------------------------------------------
// Axial column attention (over h). r18: stages DIRECTLY from natural-layout
// kn (= xpk b2, k-hat), qn (= fq4 b2, pre-scaled) and v1 with y-strided
// f32x4 reads (stride 3840 B). L2 absorbs the line overfetch (~23 KB/block).
// Compute loop identical to r12. Writes ys branch-2 interior.
// ---------------------------------------------------------------------------
__global__ __launch_bounds__(256) void axial_col_kernel(
    const float* __restrict__ knb, const float* __restrict__ qnb,
    const float* __restrict__ v1b, const float* __restrict__ lsc,
    __bf16* __restrict__ ys)
{
    __shared__ f32x4 ks[2][240];
    __shared__ f32x4 vs[2][240];
    const int bid = blockIdx.x;
    const int wi  = bid / 120;           // 0..7
    const int g   = bid % 120;
    const int h   = g % 8;
    const int xc  = g / 8;               // 0..14
    const int t = threadIdx.x;
    const int half = t >> 7, tl = t & 127;
    const int x = xc * 16 + wi * 2 + half;

    const float scale = __expf(fminf(lsc[h], LOG_MAX_C));
    const float negM2 = -scale * LOG2E;
    const size_t hb = (size_t)h * 240;
    f32x4 qreg[2] = {};

    if (tl < 120) {
#pragma unroll
        for (int s = 0; s < 2; ++s) {
            const int i = tl + s * 120;          // y position
            const size_t p4 = ((hb + i) * 240 + x) * 4;
            ks[half][i] = *(const f32x4*)(knb + p4);
            vs[half][i] = *(const f32x4*)(v1b + p4);
            qreg[s] = *(const f32x4*)(qnb + p4);
        }
    }
    __syncthreads();
    if (tl < 120) {
        float l0 = 0.f, l1 = 0.f;
        f32x4 a0 = {0, 0, 0, 0}, a1 = {0, 0, 0, 0};
#pragma unroll 4
        for (int j = 0; j < 240; ++j) {
            const f32x4 kk = ks[half][j];
            const f32x4 vv = vs[half][j];
            const float s0 = fmaf(qreg[0][0], kk[0],
                             fmaf(qreg[0][1], kk[1],
                             fmaf(qreg[0][2], kk[2],
                             fmaf(qreg[0][3], kk[3], negM2))));
            const float s1 = fmaf(qreg[1][0], kk[0],
                             fmaf(qreg[1][1], kk[1],
                             fmaf(qreg[1][2], kk[2],
                             fmaf(qreg[1][3], kk[3], negM2))));
            const float p0 = EXP2F(s0);
            const float p1 = EXP2F(s1);
            l0 += p0; l1 += p1;
            a0 += vv * p0;
            a1 += vv * p1;
        }
#pragma unroll
        for (int s = 0; s < 2; ++s) {
            const f32x4 o4 = s ? a1 * (1.0f / l1) : a0 * (1.0f / l0);
            const int i = tl + s * 120;
            union { __bf16 h4[4]; uint2 u; } o;
#pragma unroll
            for (int d = 0; d < 4; ++d) o.h4[d] = (__bf16)o4[d];
            *(uint2*)(ys + (((size_t)(i + 1) * 3 + 2) * PW + x + 1) * 32 + h * 4) = o.u;
        }
    }
}

// ---------------------------------------------------------------------------
// Pipeline (5 launches). Workspace (fp32 units):
//   xpk 96PP | xpv 96PP | fq4 96PP | xs/ys bf16 | wtf_in | wtf_f | wtf_o
// v1 lives in d_out (dead until conv_out; 32PP <= 96PP).
// axial_col reads xpk b2 / fq4 b2 / v1 directly (no transpose buffers).
// ---------------------------------------------------------------------------
extern "C" void kernel_launch(void* const* d_in, const int* in_sizes, int n_in,
                              void* d_out, int out_size, void* d_ws, size_t ws_size,
                              hipStream_t stream)
{
    const float* x     = (const float*)d_in[0];
    const float* w_in  = (const float*)d_in[1];
    const float* b_in  = (const float*)d_in[2];
    const float* w_f   = (const float*)d_in[3];
    const float* b_f   = (const float*)d_in[4];
    const float* w_out = (const float*)d_in[5];
    const float* b_out = (const float*)d_in[6];
    const float* lsc   = (const float*)d_in[7];
    const float* lrlsc = (const float*)d_in[8];
    float* out = (float*)d_out;

    float* ws  = (float*)d_ws;
    float* xpk = ws;                   // 96*PP
    float* xpv = xpk + 96 * PP;        // 96*PP
    float* fq4 = xpv + 96 * PP;        // 96*PP
    __bf16* xs     = (__bf16*)(fq4 + 96 * PP);            // 242*3*242*32 bf16
    __bf16* wtf_in = xs + (size_t)PW * 3 * PW * 32;
    __bf16* wtf_f  = wtf_in + 9 * 12 * 3 * 512;
    __bf16* wtf_o  = wtf_f + 9 * 6 * 3 * 512;
    __bf16* ys     = xs;               // alias: xs dead after conv_in_f

    float* v1  = out;                  // d_out scratch, dead until conv_out

    prep_kernel<<<392, 256, 0, stream>>>(x, w_in, w_f, w_out,
                                         xs, wtf_in, wtf_f, wtf_o);

    conv_in_f<<<2736, 256, 0, stream>>>(xs, wtf_in, wtf_f, b_in, b_f,
                                        xpk, xpv, fq4, lsc, lrlsc);

    attn_row_fused<<<5572, 256, 0, stream>>>(fq4, xpk, xpv, lsc, lrlsc, ys, v1);

    axial_col_kernel<<<960, 256, 0, stream>>>(
        xpk + 64 * PP, fq4 + 64 * PP, v1, lrlsc, ys);

    conv_out_k<<<1368, 256, 0, stream>>>(ys, wtf_o, b_out, out);
}